// Round 17
// baseline (144.822 us; speedup 1.0000x reference)
//
#include <hip/hip_runtime.h>
#include <hip/hip_bf16.h>
#include <stdint.h>

#define N_PTS 8192
#define M_EDGES 131072
#define CIN 512
#define QKV_COLS 1536

typedef __bf16 bf16x8 __attribute__((ext_vector_type(8)));
typedef float f32x4 __attribute__((ext_vector_type(4)));

#define GAS __attribute__((address_space(1)))
#define LAS __attribute__((address_space(3)))

__device__ __forceinline__ void gload_lds16(const void* g, void* l) {
  __builtin_amdgcn_global_load_lds((const GAS void*)g, (LAS void*)l, 16, 0, 0);
}

// ---- prep: cast_a | cast_bt | cast qk-tables | build vtT | edge_setup, one launch ----
__global__ __launch_bounds__(256) void prep_kernel(
    const float* __restrict__ xF, const float* __restrict__ W,
    const float* __restrict__ qt, const float* __restrict__ kt,
    const float* __restrict__ vt, const int* __restrict__ pairs,
    const float* __restrict__ xc,
    __bf16* __restrict__ A, __bf16* __restrict__ BT,
    __bf16* __restrict__ qtb, __bf16* __restrict__ ktb, __bf16* __restrict__ vtT,
    int* __restrict__ qi_a, unsigned* __restrict__ pack0, int* __restrict__ cnt) {
  __shared__ float tile[32][33];
  int b = blockIdx.x;
  int tid = threadIdx.x;
  if (b < 2048) {  // cast x_F -> bf16 A, 8 elems/thread, packed 16B store
    int base = (b * 256 + tid) * 8;
    float4 v0 = *(const float4*)(xF + base);
    float4 v1 = *(const float4*)(xF + base + 4);
    bf16x8 o;
    o[0] = (__bf16)v0.x; o[1] = (__bf16)v0.y; o[2] = (__bf16)v0.z; o[3] = (__bf16)v0.w;
    o[4] = (__bf16)v1.x; o[5] = (__bf16)v1.y; o[6] = (__bf16)v1.z; o[7] = (__bf16)v1.w;
    *(bf16x8*)(A + base) = o;
  } else if (b < 2816) {  // transpose+cast W (512x1536) -> BT (1536x512)
    int blk = b - 2048;
    int bk = blk & 15, bn = blk >> 4;
    int x = tid & 31, y = tid >> 5;
#pragma unroll
    for (int j = 0; j < 4; j++) {
      int r = y + j * 8;
      tile[r][x] = W[(size_t)(bk * 32 + r) * QKV_COLS + bn * 32 + x];
    }
    __syncthreads();
#pragma unroll
    for (int j = 0; j < 4; j++) {
      int r = y + j * 8;
      BT[(size_t)(bn * 32 + r) * CIN + bk * 32 + x] = (__bf16)tile[x][r];
    }
  } else if (b < 3104) {  // cast qt/kt tables -> [h][ab][d] bf16
    int i = (b - 2816) * 256 + tid;
    int d = i & 63, h = (i >> 6) & 7, ab = i >> 9;
    int po = (h * 144 + ab) * 64 + d;
    qtb[po] = (__bf16)qt[i];
    ktb[po] = (__bf16)kt[i];
  } else if (b < 3424) {  // vtT[h][d][p] bf16, p in [0,160), zero-padded past 144
    int i = (b - 3104) * 256 + tid;  // 8*64*160 = 81920
    int p = i % 160;
    int d = (i / 160) & 63;
    int h = i / 10240;
    vtT[i] = (p < 144) ? (__bf16)vt[p * 512 + h * 64 + d] : (__bf16)0.f;
  } else {  // edge setup
    int m = (b - 3424) * 256 + tid;
    int qi = pairs[m], ki = pairs[M_EDGES + m];
    unsigned pb = 0;
#pragma unroll
    for (int a = 0; a < 3; a++) {
      float rel = (xc[qi * 3 + a] - xc[ki * 3 + a]) / 0.05f + 24.0f;
      int bb = (int)rel;
      bb = bb < 0 ? 0 : (bb > 47 ? 47 : bb);
      pb |= (unsigned)bb << (6 * a);
    }
    qi_a[m] = qi;
    pack0[m] = (unsigned)ki | (pb << 13);
    atomicAdd(&cnt[qi], 1);
  }
}

// ---- composite: blocks 0..767 = bf16 MFMA GEMM (128x128, BK=64, swizzled, single-buf);
//      block 768 = exclusive scan of cnt + LPT counting sort (qperm). ----
__global__ __launch_bounds__(256) void gemm_scan_kernel(
    const __bf16* __restrict__ A, const __bf16* __restrict__ BT,
    const float* __restrict__ bias, __bf16* __restrict__ qb,
    __bf16* __restrict__ kv,
    const int* __restrict__ cnt, int* __restrict__ off, int* __restrict__ cursor,
    int* __restrict__ qperm) {
  __shared__ __align__(16) char At[128 * 128];  // 16KB
  __shared__ __align__(16) char Bt[128 * 128];  // 16KB
  __shared__ int wsum[4];
  __shared__ int hist2[64];
  __shared__ int bpos[64];
  int bid = blockIdx.x;
  int tid = threadIdx.x;

  if (bid == 768) {  // ---- scan + LPT sort ----
    int lane = tid & 63, w = tid >> 6;
    int local[32];
    int s = 0;
#pragma unroll
    for (int i = 0; i < 8; i++) {
      int4 v = ((const int4*)cnt)[tid * 8 + i];
      local[i * 4 + 0] = v.x; local[i * 4 + 1] = v.y;
      local[i * 4 + 2] = v.z; local[i * 4 + 3] = v.w;
      s += v.x + v.y + v.z + v.w;
    }
    int incl = s;
#pragma unroll
    for (int d = 1; d < 64; d <<= 1) {
      int t = __shfl_up(incl, d, 64);
      if (lane >= d) incl += t;
    }
    if (lane == 63) wsum[w] = incl;
    if (tid < 64) hist2[tid] = 0;
    __syncthreads();
    int woff = 0;
#pragma unroll
    for (int j = 0; j < 4; j++) woff += (j < w) ? wsum[j] : 0;
    int run = woff + incl - s;
    int base = tid * 32;
#pragma unroll
    for (int i = 0; i < 32; i++) {
      off[base + i] = run;
      cursor[base + i] = run;
      run += local[i];
      int c = local[i] < 63 ? local[i] : 63;
      atomicAdd(&hist2[c], 1);
    }
    if (tid == 255) off[N_PTS] = run;
    __syncthreads();
    if (tid < 64) {  // descending-count exclusive positions
      int p = 0;
      for (int bb = 63; bb > tid; bb--) p += hist2[bb];
      bpos[tid] = p;
    }
    __syncthreads();
#pragma unroll
    for (int i = 0; i < 32; i++) {
      int c = local[i] < 63 ? local[i] : 63;
      int pos = atomicAdd(&bpos[c], 1);
      qperm[pos] = base + i;
    }
    return;
  }

  int bn = bid % 12, bm = bid / 12;  // bn fastest: consecutive blocks share A tile
  int w = tid >> 6, l = tid & 63;
  int wm = w & 1, wn = w >> 1;
  f32x4 acc[4][4] = {};
  const char* Ab = (const char*)A;
  const char* Bb = (const char*)BT;
  int lr = l & 15;
  int lk = (l >> 4) * 16;
  int xr = (lr & 7) << 4;

  for (int kt = 0; kt < 8; kt++) {
#pragma unroll
    for (int r = 0; r < 4; r++) {
      int flat = r * 4096 + tid * 16;
      int row = flat >> 7, colb = flat & 127;
      int gcolb = colb ^ ((row & 7) << 4);
      gload_lds16(Ab + ((size_t)(bm * 128 + row) * CIN + kt * 64) * 2 + gcolb,
                  At + r * 4096 + w * 1024);
      gload_lds16(Bb + ((size_t)(bn * 128 + row) * CIN + kt * 64) * 2 + gcolb,
                  Bt + r * 4096 + w * 1024);
    }
    __syncthreads();
#pragma unroll
    for (int ks = 0; ks < 2; ks++) {
      bf16x8 af[4], bfr[4];
      int cs = (ks * 64 + lk) ^ xr;
#pragma unroll
      for (int mf = 0; mf < 4; mf++) af[mf] = *(const bf16x8*)(At + (wm * 64 + mf * 16 + lr) * 128 + cs);
#pragma unroll
      for (int nf = 0; nf < 4; nf++) bfr[nf] = *(const bf16x8*)(Bt + (wn * 64 + nf * 16 + lr) * 128 + cs);
#pragma unroll
      for (int mf = 0; mf < 4; mf++)
#pragma unroll
        for (int nf = 0; nf < 4; nf++)
          acc[mf][nf] = __builtin_amdgcn_mfma_f32_16x16x32_bf16(af[mf], bfr[nf], acc[mf][nf], 0, 0, 0);
    }
    __syncthreads();
  }

  int lg = l >> 4;
#pragma unroll
  for (int mf = 0; mf < 4; mf++) {
#pragma unroll
    for (int nf = 0; nf < 4; nf++) {
      int gc = bn * 128 + wn * 64 + nf * 16 + lr;
      float b = bias[gc];
      int which = gc >> 9;
      int col = gc & 511;
      float scale = which == 0 ? 0.125f : 1.0f;
#pragma unroll
      for (int j = 0; j < 4; j++) {
        int gr = bm * 128 + wm * 64 + mf * 16 + lg * 4 + j;
        float val = (acc[mf][nf][j] + b) * scale;
        if (which == 0) qb[(size_t)gr * 512 + col] = (__bf16)val;
        else kv[(size_t)gr * 1024 + (which == 2 ? 512 : 0) + col] = (__bf16)val;
      }
    }
  }
}

// ---- fused: blocks 0..511 = scatter permutation (epack); blocks 512..1535 = table_dot.
__global__ __launch_bounds__(256) void td_scatter_kernel(
    const __bf16* __restrict__ qb, const __bf16* __restrict__ kv,
    const __bf16* __restrict__ qtb, const __bf16* __restrict__ ktb,
    __bf16* __restrict__ qdot, __bf16* __restrict__ kdot,
    const int* __restrict__ qi_a, const unsigned* __restrict__ pack0,
    int* __restrict__ cursor, unsigned* __restrict__ epack) {
  __shared__ __align__(16) char As[128 * 128];
  __shared__ __align__(16) char Bs[144 * 128];
  int bid = blockIdx.x;
  int tid = threadIdx.x;

  if (bid < 512) {  // scatter: pure permutation into CSR order
    int m = bid * 256 + tid;
    int qi = qi_a[m];
    int pos = atomicAdd(&cursor[qi], 1);
    epack[pos] = pack0[m];
    return;
  }

  int td = bid - 512;
  int nt = td & 63, h = (td >> 6) & 7, z = td >> 9;
  const __bf16* src = z ? kv : qb;
  const __bf16* tab = z ? ktb : qtb;
  __bf16* out = z ? kdot : qdot;
  size_t SB = z ? 2048 : 1024;  // row stride in bytes
  int w = tid >> 6, l = tid & 63;
  const char* sb = (const char*)src;
  const char* tb = (const char*)tab + (size_t)h * 144 * 128;
#pragma unroll
  for (int p = 0; p < 4; p++) {
    int flat = p * 4096 + tid * 16;
    int row = flat >> 7, colb = flat & 127;
    int gcolb = colb ^ ((row & 7) << 4);
    gload_lds16(sb + (size_t)(nt * 128 + row) * SB + h * 128 + gcolb, As + p * 4096 + w * 1024);
    gload_lds16(tb + row * 128 + gcolb, Bs + p * 4096 + w * 1024);
  }
  if (w < 2) {
    int flat = 16384 + w * 1024 + l * 16;
    int row = flat >> 7, colb = flat & 127;
    int gcolb = colb ^ ((row & 7) << 4);
    gload_lds16(tb + row * 128 + gcolb, Bs + 16384 + w * 1024);
  }
  __syncthreads();

  f32x4 acc[2][9] = {};
  int lr = l & 15, lk = (l >> 4) * 16;
  int xr = (lr & 7) << 4;
#pragma unroll
  for (int ks = 0; ks < 2; ks++) {
    bf16x8 af[2], bf[9];
    int cs = (ks * 64 + lk) ^ xr;
#pragma unroll
    for (int mf = 0; mf < 2; mf++)
      af[mf] = *(const bf16x8*)(As + (w * 32 + mf * 16 + lr) * 128 + cs);
#pragma unroll
    for (int nf = 0; nf < 9; nf++)
      bf[nf] = *(const bf16x8*)(Bs + (nf * 16 + lr) * 128 + cs);
#pragma unroll
    for (int mf = 0; mf < 2; mf++)
#pragma unroll
      for (int nf = 0; nf < 9; nf++)
        acc[mf][nf] = __builtin_amdgcn_mfma_f32_16x16x32_bf16(af[mf], bf[nf], acc[mf][nf], 0, 0, 0);
  }

  int lg = l >> 4;
#pragma unroll
  for (int mf = 0; mf < 2; mf++)
#pragma unroll
    for (int nf = 0; nf < 9; nf++)
#pragma unroll
      for (int j = 0; j < 4; j++) {
        int n = nt * 128 + w * 32 + mf * 16 + lg * 4 + j;
        int ab = nf * 16 + lr;
        out[(size_t)n * 1152 + ab * 8 + h] = (__bf16)acc[mf][nf][j];
      }
}

// ---- fused attention: block = qperm[blockIdx] (LPT order), 256 threads = 4 waves.
// lanes = 8 heads x 8 dim-groups; kv rows 2KB contiguous. q-side table bias served
// from an LDS-staged copy of the block-uniform qdot row; k-side gathered inline.
// Wave-uniform epack s_load software-pipelined one iteration ahead. ----
__global__ __launch_bounds__(256) void attn_kernel(
    const __bf16* __restrict__ qb, const __bf16* __restrict__ kv,
    const __bf16* __restrict__ qdot, const __bf16* __restrict__ kdot,
    const int* __restrict__ off, const unsigned* __restrict__ epack,
    const int* __restrict__ qperm,
    __bf16* __restrict__ numb, float* __restrict__ den, __bf16* __restrict__ Hb) {
  __shared__ float hist[8 * 164];   // padded rows (breaks 8-way bank conflict)
  __shared__ float part[4][512];    // per-wave num partials
  __shared__ float dpart[4][8];     // per-wave den partials
  __shared__ __align__(16) __bf16 qd_s[1152];  // block-uniform qdot row
  int n = qperm[blockIdx.x];
  int tid = threadIdx.x;
  int w = tid >> 6, l = tid & 63;
  int h = l >> 3, dg = l & 7;       // lane = (head, dim-group)

  for (int i = tid; i < 8 * 164; i += 256) hist[i] = 0.f;
  if (tid < 144)  // stage qdot row (2304B) into LDS, 16B per lane
    *(bf16x8*)(qd_s + tid * 8) = *(const bf16x8*)(qdot + (size_t)n * 1152 + tid * 8);
  __syncthreads();

  bf16x8 q8 = *(const bf16x8*)(qb + (n << 9) + l * 8);
  float qv[8];
#pragma unroll
  for (int j = 0; j < 8; j++) qv[j] = (float)q8[j];

  float acc[8] = {0.f, 0.f, 0.f, 0.f, 0.f, 0.f, 0.f, 0.f};
  float dn = 0.f;
  int e0 = off[n], e1 = off[n + 1];
  int axis = dg < 3 ? dg : dg - 3;  // table axis handled by this lane (dg<6)
  int tsh = 6 * axis;

  int e = e0 + w;
  unsigned pk_next = (e < e1) ? epack[__builtin_amdgcn_readfirstlane(e)] : 0u;
  for (; e < e1; e += 4) {
    unsigned pk = pk_next;
    int en = e + 4;
    if (en < e1) pk_next = epack[__builtin_amdgcn_readfirstlane(en)];  // prefetch s_load
    int ki = pk & 8191;
    unsigned pb = pk >> 13;
    bf16x8 k8 = *(const bf16x8*)(kv + ((size_t)ki << 10) + l * 8);        // 2KB row,
    bf16x8 v8 = *(const bf16x8*)(kv + ((size_t)ki << 10) + 512 + l * 8);  // contiguous
    int bin = (int)((pb >> tsh) & 63u);
    int idx = (axis * 48 + bin) * 8 + h;
    float p;
    if (dg < 3) p = (float)qd_s[idx];                       // LDS, block-uniform row
    else if (dg < 6) p = (float)kdot[(size_t)ki * 1152 + idx];
    else p = 0.f;
#pragma unroll
    for (int j = 0; j < 8; j++) p += qv[j] * (float)k8[j];
    p += __shfl_xor(p, 1, 64);
    p += __shfl_xor(p, 2, 64);
    p += __shfl_xor(p, 4, 64);   // now p = full logit for (edge e, head h)
    float x = __expf(p);
    dn += x;
#pragma unroll
    for (int j = 0; j < 8; j++) acc[j] += x * (float)v8[j];
    if (dg < 3) {                // 24 lanes: one atomic per (head, axis) in parallel
      atomicAdd(hist + h * 164 + dg * 48 + (int)((pb >> (6 * dg)) & 63u), x);
    }
  }

  // per-wave partials -> LDS, then cross-wave reduce
  f32x4 a0 = {acc[0], acc[1], acc[2], acc[3]};
  f32x4 a1 = {acc[4], acc[5], acc[6], acc[7]};
  *(f32x4*)&part[w][l * 8] = a0;
  *(f32x4*)&part[w][l * 8 + 4] = a1;
  if (dg == 0) dpart[w][h] = dn;
  __syncthreads();

#pragma unroll
  for (int half = 0; half < 2; half++) {
    int idx = tid + half * 256;
    float s = part[0][idx] + part[1][idx] + part[2][idx] + part[3][idx];
    numb[(n << 9) + idx] = (__bf16)s;
  }
  if (tid < 8) {
    den[n * 8 + tid] = dpart[0][tid] + dpart[1][tid] + dpart[2][tid] + dpart[3][tid];
  }
  if (tid < 160) {  // vectorized Hb store: 8 consecutive bins per lane
    int row = tid / 20, p = (tid % 20) * 8;
    const float* hp = hist + row * 164 + p;
    bf16x8 o;
#pragma unroll
    for (int j = 0; j < 8; j++) o[j] = (__bf16)hp[j];
    *(bf16x8*)(Hb + (size_t)n * 1280 + row * 160 + p) = o;
  }
}

// ---- finish: out = (numb + Hb @ vtT) * invden.  Per block: 128 queries x 1 head. ----
__global__ __launch_bounds__(256) void finish_kernel(const __bf16* __restrict__ Hb,
                                                     const __bf16* __restrict__ vtT,
                                                     const __bf16* __restrict__ numb,
                                                     const float* __restrict__ den,
                                                     float* __restrict__ out) {
  __shared__ __align__(16) char As[2][128 * 64];  // 2x8KB
  __shared__ __align__(16) char Bs[2][64 * 64];   // 2x4KB
  int nt = blockIdx.x, h = blockIdx.y;
  int tid = threadIdx.x, w = tid >> 6, l = tid & 63;
  int lr = l & 15, lk = (l >> 4) * 16;
  int xr = (lr & 3) << 4;
  const char* Ab = (const char*)Hb;
  const char* Bb = (const char*)vtT;
  f32x4 acc[2][4] = {};

  auto stage = [&](int tk, int buf) {
#pragma unroll
    for (int c = 0; c < 2; c++) {
      int flat = c * 4096 + tid * 16;
      int row = flat >> 6, colb = flat & 63;
      int gcolb = colb ^ ((row & 3) << 4);
      gload_lds16(Ab + ((size_t)(nt * 128 + row) * 1280 + h * 160 + tk * 32) * 2 + gcolb,
                  As[buf] + c * 4096 + w * 1024);
    }
    {
      int flat = tid * 16;
      int row = flat >> 6, colb = flat & 63;
      int gcolb = colb ^ ((row & 3) << 4);
      gload_lds16(Bb + ((size_t)(h * 64 + row) * 160 + tk * 32) * 2 + gcolb,
                  Bs[buf] + w * 1024);
    }
  };

  stage(0, 0);
  __syncthreads();
  int cur = 0;
  for (int kt = 0; kt < 5; kt++) {
    if (kt < 4) stage(kt + 1, cur ^ 1);
    bf16x8 af[2], bf[4];
    int cs = lk ^ xr;
#pragma unroll
    for (int mf = 0; mf < 2; mf++) af[mf] = *(const bf16x8*)(As[cur] + (w * 32 + mf * 16 + lr) * 64 + cs);
#pragma unroll
    for (int nf = 0; nf < 4; nf++) bf[nf] = *(const bf16x8*)(Bs[cur] + (nf * 16 + lr) * 64 + cs);
#pragma unroll
    for (int mf = 0; mf < 2; mf++)
#pragma unroll
      for (int nf = 0; nf < 4; nf++)
        acc[mf][nf] = __builtin_amdgcn_mfma_f32_16x16x32_bf16(af[mf], bf[nf], acc[mf][nf], 0, 0, 0);
    __syncthreads();
    cur ^= 1;
  }

  int lg = l >> 4;
#pragma unroll
  for (int mf = 0; mf < 2; mf++) {
#pragma unroll
    for (int j = 0; j < 4; j++) {
      int n = nt * 128 + w * 32 + mf * 16 + lg * 4 + j;
      float dnv = den[n * 8 + h];
      float inv = dnv > 0.f ? 1.f / dnv : 0.f;
#pragma unroll
      for (int nf = 0; nf < 4; nf++) {
        int gi = (n << 9) + h * 64 + nf * 16 + lr;
        out[gi] = ((float)numb[gi] + acc[mf][nf][j]) * inv;
      }
    }
  }
}

extern "C" void kernel_launch(void* const* d_in, const int* in_sizes, int n_in,
                              void* d_out, int out_size, void* d_ws, size_t ws_size,
                              hipStream_t stream) {
  const float* xF = (const float*)d_in[0];
  const float* xC = (const float*)d_in[1];
  const int* pairs = (const int*)d_in[2];
  const float* W = (const float*)d_in[3];
  const float* bias = (const float*)d_in[4];
  const float* qt = (const float*)d_in[5];
  const float* kt = (const float*)d_in[6];
  const float* vt = (const float*)d_in[7];
  float* out = (float*)d_out;

  char* ws = (char*)d_ws;
  size_t o = 0;
  auto alloc = [&](size_t bytes) {
    void* p = ws + o;
    o = (o + bytes + 255) & ~(size_t)255;
    return p;
  };
  // region 0: A+BT live only until gemm; Hb (written by attn, later) aliases them.
  char* region0 = (char*)alloc((size_t)N_PTS * 1280 * 2);  // 20.97 MB
  __bf16* A = (__bf16*)region0;                      // 8 MB
  __bf16* BT = (__bf16*)(region0 + (size_t)N_PTS * CIN * 2);  // 1.5 MB
  __bf16* Hb = (__bf16*)region0;                     // aliases A/BT after gemm
  __bf16* qb = (__bf16*)alloc((size_t)N_PTS * 512 * 2);
  __bf16* kv = (__bf16*)alloc((size_t)N_PTS * 1024 * 2);  // k|v interleaved, 2KB rows
  __bf16* qtb = (__bf16*)alloc((size_t)8 * 144 * 64 * 2);
  __bf16* ktb = (__bf16*)alloc((size_t)8 * 144 * 64 * 2);
  __bf16* vtT = (__bf16*)alloc((size_t)8 * 64 * 160 * 2);
  __bf16* qdot = (__bf16*)alloc((size_t)N_PTS * 1152 * 2);
  __bf16* kdot = (__bf16*)alloc((size_t)N_PTS * 1152 * 2);
  __bf16* numb = (__bf16*)alloc((size_t)N_PTS * 512 * 2);
  float* den = (float*)alloc((size_t)N_PTS * 8 * 4);
  int* qi_a = (int*)alloc(M_EDGES * 4);
  unsigned* pack0 = (unsigned*)alloc(M_EDGES * 4);
  unsigned* epack = (unsigned*)alloc(M_EDGES * 4);
  int* cnt = (int*)alloc(N_PTS * 4);
  int* off = (int*)alloc((N_PTS + 1) * 4);
  int* cursor = (int*)alloc(N_PTS * 4);
  int* qperm = (int*)alloc(N_PTS * 4);

  hipMemsetAsync(cnt, 0, N_PTS * 4, stream);

  prep_kernel<<<3936, 256, 0, stream>>>(xF, W, qt, kt, vt, pairs, xC,
                                        A, BT, qtb, ktb, vtT, qi_a, pack0, cnt);
  gemm_scan_kernel<<<769, 256, 0, stream>>>(A, BT, bias, qb, kv, cnt, off, cursor, qperm);
  td_scatter_kernel<<<1536, 256, 0, stream>>>(qb, kv, qtb, ktb, qdot, kdot,
                                              qi_a, pack0, cursor, epack);
  attn_kernel<<<N_PTS, 256, 0, stream>>>(qb, kv, qdot, kdot, off, epack, qperm,
                                         numb, den, Hb);
  finish_kernel<<<dim3(N_PTS / 128, 8), 256, 0, stream>>>(Hb, vtT, numb, den, out);
}

// Round 18
// 142.237 us; speedup vs baseline: 1.0182x; 1.0182x over previous
//
#include <hip/hip_runtime.h>
#include <hip/hip_bf16.h>
#include <stdint.h>

#define N_PTS 8192
#define M_EDGES 131072
#define CIN 512
#define QKV_COLS 1536

typedef __bf16 bf16x8 __attribute__((ext_vector_type(8)));
typedef float f32x4 __attribute__((ext_vector_type(4)));

#define GAS __attribute__((address_space(1)))
#define LAS __attribute__((address_space(3)))

__device__ __forceinline__ void gload_lds16(const void* g, void* l) {
  __builtin_amdgcn_global_load_lds((const GAS void*)g, (LAS void*)l, 16, 0, 0);
}

// ---- prep: cast_a | cast_bt | cast qk-tables | build vtT | edge_setup, one launch ----
__global__ __launch_bounds__(256) void prep_kernel(
    const float* __restrict__ xF, const float* __restrict__ W,
    const float* __restrict__ qt, const float* __restrict__ kt,
    const float* __restrict__ vt, const int* __restrict__ pairs,
    const float* __restrict__ xc,
    __bf16* __restrict__ A, __bf16* __restrict__ BT,
    __bf16* __restrict__ qtb, __bf16* __restrict__ ktb, __bf16* __restrict__ vtT,
    int* __restrict__ qi_a, unsigned* __restrict__ pack0, int* __restrict__ cnt) {
  __shared__ float tile[32][33];
  int b = blockIdx.x;
  int tid = threadIdx.x;
  if (b < 2048) {  // cast x_F -> bf16 A, 8 elems/thread, packed 16B store
    int base = (b * 256 + tid) * 8;
    float4 v0 = *(const float4*)(xF + base);
    float4 v1 = *(const float4*)(xF + base + 4);
    bf16x8 o;
    o[0] = (__bf16)v0.x; o[1] = (__bf16)v0.y; o[2] = (__bf16)v0.z; o[3] = (__bf16)v0.w;
    o[4] = (__bf16)v1.x; o[5] = (__bf16)v1.y; o[6] = (__bf16)v1.z; o[7] = (__bf16)v1.w;
    *(bf16x8*)(A + base) = o;
  } else if (b < 2816) {  // transpose+cast W (512x1536) -> BT (1536x512)
    int blk = b - 2048;
    int bk = blk & 15, bn = blk >> 4;
    int x = tid & 31, y = tid >> 5;
#pragma unroll
    for (int j = 0; j < 4; j++) {
      int r = y + j * 8;
      tile[r][x] = W[(size_t)(bk * 32 + r) * QKV_COLS + bn * 32 + x];
    }
    __syncthreads();
#pragma unroll
    for (int j = 0; j < 4; j++) {
      int r = y + j * 8;
      BT[(size_t)(bn * 32 + r) * CIN + bk * 32 + x] = (__bf16)tile[x][r];
    }
  } else if (b < 3104) {  // cast qt/kt tables -> [h][ab][d] bf16
    int i = (b - 2816) * 256 + tid;
    int d = i & 63, h = (i >> 6) & 7, ab = i >> 9;
    int po = (h * 144 + ab) * 64 + d;
    qtb[po] = (__bf16)qt[i];
    ktb[po] = (__bf16)kt[i];
  } else if (b < 3424) {  // vtT[h][d][p] bf16, p in [0,160), zero-padded past 144
    int i = (b - 3104) * 256 + tid;  // 8*64*160 = 81920
    int p = i % 160;
    int d = (i / 160) & 63;
    int h = i / 10240;
    vtT[i] = (p < 144) ? (__bf16)vt[p * 512 + h * 64 + d] : (__bf16)0.f;
  } else {  // edge setup
    int m = (b - 3424) * 256 + tid;
    int qi = pairs[m], ki = pairs[M_EDGES + m];
    unsigned pb = 0;
#pragma unroll
    for (int a = 0; a < 3; a++) {
      float rel = (xc[qi * 3 + a] - xc[ki * 3 + a]) / 0.05f + 24.0f;
      int bb = (int)rel;
      bb = bb < 0 ? 0 : (bb > 47 ? 47 : bb);
      pb |= (unsigned)bb << (6 * a);
    }
    qi_a[m] = qi;
    pack0[m] = (unsigned)ki | (pb << 13);
    atomicAdd(&cnt[qi], 1);
  }
}

// ---- composite: blocks 0..767 = bf16 MFMA GEMM (128x128, BK=64, swizzled, single-buf);
//      block 768 = exclusive scan of cnt + LPT counting sort (qperm). ----
__global__ __launch_bounds__(256) void gemm_scan_kernel(
    const __bf16* __restrict__ A, const __bf16* __restrict__ BT,
    const float* __restrict__ bias, __bf16* __restrict__ qb,
    __bf16* __restrict__ kv,
    const int* __restrict__ cnt, int* __restrict__ off, int* __restrict__ cursor,
    int* __restrict__ qperm) {
  __shared__ __align__(16) char At[128 * 128];  // 16KB
  __shared__ __align__(16) char Bt[128 * 128];  // 16KB
  __shared__ int wsum[4];
  __shared__ int hist2[64];
  __shared__ int bpos[64];
  int bid = blockIdx.x;
  int tid = threadIdx.x;

  if (bid == 768) {  // ---- scan + LPT sort ----
    int lane = tid & 63, w = tid >> 6;
    int local[32];
    int s = 0;
#pragma unroll
    for (int i = 0; i < 8; i++) {
      int4 v = ((const int4*)cnt)[tid * 8 + i];
      local[i * 4 + 0] = v.x; local[i * 4 + 1] = v.y;
      local[i * 4 + 2] = v.z; local[i * 4 + 3] = v.w;
      s += v.x + v.y + v.z + v.w;
    }
    int incl = s;
#pragma unroll
    for (int d = 1; d < 64; d <<= 1) {
      int t = __shfl_up(incl, d, 64);
      if (lane >= d) incl += t;
    }
    if (lane == 63) wsum[w] = incl;
    if (tid < 64) hist2[tid] = 0;
    __syncthreads();
    int woff = 0;
#pragma unroll
    for (int j = 0; j < 4; j++) woff += (j < w) ? wsum[j] : 0;
    int run = woff + incl - s;
    int base = tid * 32;
#pragma unroll
    for (int i = 0; i < 32; i++) {
      off[base + i] = run;
      cursor[base + i] = run;
      run += local[i];
      int c = local[i] < 63 ? local[i] : 63;
      atomicAdd(&hist2[c], 1);
    }
    if (tid == 255) off[N_PTS] = run;
    __syncthreads();
    if (tid < 64) {  // descending-count exclusive positions
      int p = 0;
      for (int bb = 63; bb > tid; bb--) p += hist2[bb];
      bpos[tid] = p;
    }
    __syncthreads();
#pragma unroll
    for (int i = 0; i < 32; i++) {
      int c = local[i] < 63 ? local[i] : 63;
      int pos = atomicAdd(&bpos[c], 1);
      qperm[pos] = base + i;
    }
    return;
  }

  int bn = bid % 12, bm = bid / 12;  // bn fastest: consecutive blocks share A tile
  int w = tid >> 6, l = tid & 63;
  int wm = w & 1, wn = w >> 1;
  f32x4 acc[4][4] = {};
  const char* Ab = (const char*)A;
  const char* Bb = (const char*)BT;
  int lr = l & 15;
  int lk = (l >> 4) * 16;
  int xr = (lr & 7) << 4;

  for (int kt = 0; kt < 8; kt++) {
#pragma unroll
    for (int r = 0; r < 4; r++) {
      int flat = r * 4096 + tid * 16;
      int row = flat >> 7, colb = flat & 127;
      int gcolb = colb ^ ((row & 7) << 4);
      gload_lds16(Ab + ((size_t)(bm * 128 + row) * CIN + kt * 64) * 2 + gcolb,
                  At + r * 4096 + w * 1024);
      gload_lds16(Bb + ((size_t)(bn * 128 + row) * CIN + kt * 64) * 2 + gcolb,
                  Bt + r * 4096 + w * 1024);
    }
    __syncthreads();
#pragma unroll
    for (int ks = 0; ks < 2; ks++) {
      bf16x8 af[4], bfr[4];
      int cs = (ks * 64 + lk) ^ xr;
#pragma unroll
      for (int mf = 0; mf < 4; mf++) af[mf] = *(const bf16x8*)(At + (wm * 64 + mf * 16 + lr) * 128 + cs);
#pragma unroll
      for (int nf = 0; nf < 4; nf++) bfr[nf] = *(const bf16x8*)(Bt + (wn * 64 + nf * 16 + lr) * 128 + cs);
#pragma unroll
      for (int mf = 0; mf < 4; mf++)
#pragma unroll
        for (int nf = 0; nf < 4; nf++)
          acc[mf][nf] = __builtin_amdgcn_mfma_f32_16x16x32_bf16(af[mf], bfr[nf], acc[mf][nf], 0, 0, 0);
    }
    __syncthreads();
  }

  int lg = l >> 4;
#pragma unroll
  for (int mf = 0; mf < 4; mf++) {
#pragma unroll
    for (int nf = 0; nf < 4; nf++) {
      int gc = bn * 128 + wn * 64 + nf * 16 + lr;
      float b = bias[gc];
      int which = gc >> 9;
      int col = gc & 511;
      float scale = which == 0 ? 0.125f : 1.0f;
#pragma unroll
      for (int j = 0; j < 4; j++) {
        int gr = bm * 128 + wm * 64 + mf * 16 + lg * 4 + j;
        float val = (acc[mf][nf][j] + b) * scale;
        if (which == 0) qb[(size_t)gr * 512 + col] = (__bf16)val;
        else kv[(size_t)gr * 1024 + (which == 2 ? 512 : 0) + col] = (__bf16)val;
      }
    }
  }
}

// ---- fused: blocks 0..511 = scatter permutation (epack); blocks 512..1535 = table_dot.
__global__ __launch_bounds__(256) void td_scatter_kernel(
    const __bf16* __restrict__ qb, const __bf16* __restrict__ kv,
    const __bf16* __restrict__ qtb, const __bf16* __restrict__ ktb,
    __bf16* __restrict__ qdot, __bf16* __restrict__ kdot,
    const int* __restrict__ qi_a, const unsigned* __restrict__ pack0,
    int* __restrict__ cursor, unsigned* __restrict__ epack) {
  __shared__ __align__(16) char As[128 * 128];
  __shared__ __align__(16) char Bs[144 * 128];
  int bid = blockIdx.x;
  int tid = threadIdx.x;

  if (bid < 512) {  // scatter: pure permutation into CSR order
    int m = bid * 256 + tid;
    int qi = qi_a[m];
    int pos = atomicAdd(&cursor[qi], 1);
    epack[pos] = pack0[m];
    return;
  }

  int td = bid - 512;
  int nt = td & 63, h = (td >> 6) & 7, z = td >> 9;
  const __bf16* src = z ? kv : qb;
  const __bf16* tab = z ? ktb : qtb;
  __bf16* out = z ? kdot : qdot;
  size_t SB = z ? 2048 : 1024;  // row stride in bytes
  int w = tid >> 6, l = tid & 63;
  const char* sb = (const char*)src;
  const char* tb = (const char*)tab + (size_t)h * 144 * 128;
#pragma unroll
  for (int p = 0; p < 4; p++) {
    int flat = p * 4096 + tid * 16;
    int row = flat >> 7, colb = flat & 127;
    int gcolb = colb ^ ((row & 7) << 4);
    gload_lds16(sb + (size_t)(nt * 128 + row) * SB + h * 128 + gcolb, As + p * 4096 + w * 1024);
    gload_lds16(tb + row * 128 + gcolb, Bs + p * 4096 + w * 1024);
  }
  if (w < 2) {
    int flat = 16384 + w * 1024 + l * 16;
    int row = flat >> 7, colb = flat & 127;
    int gcolb = colb ^ ((row & 7) << 4);
    gload_lds16(tb + row * 128 + gcolb, Bs + 16384 + w * 1024);
  }
  __syncthreads();

  f32x4 acc[2][9] = {};
  int lr = l & 15, lk = (l >> 4) * 16;
  int xr = (lr & 7) << 4;
#pragma unroll
  for (int ks = 0; ks < 2; ks++) {
    bf16x8 af[2], bf[9];
    int cs = (ks * 64 + lk) ^ xr;
#pragma unroll
    for (int mf = 0; mf < 2; mf++)
      af[mf] = *(const bf16x8*)(As + (w * 32 + mf * 16 + lr) * 128 + cs);
#pragma unroll
    for (int nf = 0; nf < 9; nf++)
      bf[nf] = *(const bf16x8*)(Bs + (nf * 16 + lr) * 128 + cs);
#pragma unroll
    for (int mf = 0; mf < 2; mf++)
#pragma unroll
      for (int nf = 0; nf < 9; nf++)
        acc[mf][nf] = __builtin_amdgcn_mfma_f32_16x16x32_bf16(af[mf], bf[nf], acc[mf][nf], 0, 0, 0);
  }

  int lg = l >> 4;
#pragma unroll
  for (int mf = 0; mf < 2; mf++)
#pragma unroll
    for (int nf = 0; nf < 9; nf++)
#pragma unroll
      for (int j = 0; j < 4; j++) {
        int n = nt * 128 + w * 32 + mf * 16 + lg * 4 + j;
        int ab = nf * 16 + lr;
        out[(size_t)n * 1152 + ab * 8 + h] = (__bf16)acc[mf][nf][j];
      }
}

// ---- fused attention: block = qperm[blockIdx] (LPT order), 256 threads = 4 waves.
// lanes = 8 heads x 8 dim-groups; kv rows 2KB contiguous. Table bias gathered inline;
// wave-uniform epack s_load software-pipelined one iteration ahead. ----
__global__ __launch_bounds__(256) void attn_kernel(
    const __bf16* __restrict__ qb, const __bf16* __restrict__ kv,
    const __bf16* __restrict__ qdot, const __bf16* __restrict__ kdot,
    const int* __restrict__ off, const unsigned* __restrict__ epack,
    const int* __restrict__ qperm,
    __bf16* __restrict__ numb, float* __restrict__ den, __bf16* __restrict__ Hb) {
  __shared__ float hist[8 * 164];   // padded rows (breaks 8-way bank conflict)
  __shared__ float part[4][512];    // per-wave num partials
  __shared__ float dpart[4][8];     // per-wave den partials
  int n = qperm[blockIdx.x];
  int tid = threadIdx.x;
  int w = tid >> 6, l = tid & 63;
  int h = l >> 3, dg = l & 7;       // lane = (head, dim-group)

  for (int i = tid; i < 8 * 164; i += 256) hist[i] = 0.f;
  __syncthreads();

  bf16x8 q8 = *(const bf16x8*)(qb + (n << 9) + l * 8);
  float qv[8];
#pragma unroll
  for (int j = 0; j < 8; j++) qv[j] = (float)q8[j];

  float acc[8] = {0.f, 0.f, 0.f, 0.f, 0.f, 0.f, 0.f, 0.f};
  float dn = 0.f;
  int e0 = off[n], e1 = off[n + 1];
  const __bf16* qd_row = qdot + (size_t)n * 1152;
  int axis = dg < 3 ? dg : dg - 3;  // table axis handled by this lane (dg<6)
  int tsh = 6 * axis;

  int e = e0 + w;
  unsigned pk_next = (e < e1) ? epack[__builtin_amdgcn_readfirstlane(e)] : 0u;
  for (; e < e1; e += 4) {
    unsigned pk = pk_next;
    int en = e + 4;
    if (en < e1) pk_next = epack[__builtin_amdgcn_readfirstlane(en)];  // prefetch s_load
    int ki = pk & 8191;
    unsigned pb = pk >> 13;
    bf16x8 k8 = *(const bf16x8*)(kv + ((size_t)ki << 10) + l * 8);        // 2KB row,
    bf16x8 v8 = *(const bf16x8*)(kv + ((size_t)ki << 10) + 512 + l * 8);  // contiguous
    int bin = (int)((pb >> tsh) & 63u);
    int idx = (axis * 48 + bin) * 8 + h;
    const __bf16* tbl = dg < 3 ? qd_row : (kdot + (size_t)ki * 1152);
    float p = (dg < 6) ? (float)tbl[idx] : 0.f;
#pragma unroll
    for (int j = 0; j < 8; j++) p += qv[j] * (float)k8[j];
    p += __shfl_xor(p, 1, 64);
    p += __shfl_xor(p, 2, 64);
    p += __shfl_xor(p, 4, 64);   // now p = full logit for (edge e, head h)
    float x = __expf(p);
    dn += x;
#pragma unroll
    for (int j = 0; j < 8; j++) acc[j] += x * (float)v8[j];
    if (dg < 3) {                // 24 lanes: one atomic per (head, axis) in parallel
      atomicAdd(hist + h * 164 + dg * 48 + (int)((pb >> (6 * dg)) & 63u), x);
    }
  }

  // per-wave partials -> LDS, then cross-wave reduce
  f32x4 a0 = {acc[0], acc[1], acc[2], acc[3]};
  f32x4 a1 = {acc[4], acc[5], acc[6], acc[7]};
  *(f32x4*)&part[w][l * 8] = a0;
  *(f32x4*)&part[w][l * 8 + 4] = a1;
  if (dg == 0) dpart[w][h] = dn;
  __syncthreads();

#pragma unroll
  for (int half = 0; half < 2; half++) {
    int idx = tid + half * 256;
    float s = part[0][idx] + part[1][idx] + part[2][idx] + part[3][idx];
    numb[(n << 9) + idx] = (__bf16)s;
  }
  if (tid < 8) {
    den[n * 8 + tid] = dpart[0][tid] + dpart[1][tid] + dpart[2][tid] + dpart[3][tid];
  }
  if (tid < 160) {  // vectorized Hb store: 8 consecutive bins per lane
    int row = tid / 20, p = (tid % 20) * 8;
    const float* hp = hist + row * 164 + p;
    bf16x8 o;
#pragma unroll
    for (int j = 0; j < 8; j++) o[j] = (__bf16)hp[j];
    *(bf16x8*)(Hb + (size_t)n * 1280 + row * 160 + p) = o;
  }
}

// ---- finish: out = (numb + Hb @ vtT) * invden.  Per block: 128 queries x 1 head. ----
__global__ __launch_bounds__(256) void finish_kernel(const __bf16* __restrict__ Hb,
                                                     const __bf16* __restrict__ vtT,
                                                     const __bf16* __restrict__ numb,
                                                     const float* __restrict__ den,
                                                     float* __restrict__ out) {
  __shared__ __align__(16) char As[2][128 * 64];  // 2x8KB
  __shared__ __align__(16) char Bs[2][64 * 64];   // 2x4KB
  int nt = blockIdx.x, h = blockIdx.y;
  int tid = threadIdx.x, w = tid >> 6, l = tid & 63;
  int lr = l & 15, lk = (l >> 4) * 16;
  int xr = (lr & 3) << 4;
  const char* Ab = (const char*)Hb;
  const char* Bb = (const char*)vtT;
  f32x4 acc[2][4] = {};

  auto stage = [&](int tk, int buf) {
#pragma unroll
    for (int c = 0; c < 2; c++) {
      int flat = c * 4096 + tid * 16;
      int row = flat >> 6, colb = flat & 63;
      int gcolb = colb ^ ((row & 3) << 4);
      gload_lds16(Ab + ((size_t)(nt * 128 + row) * 1280 + h * 160 + tk * 32) * 2 + gcolb,
                  As[buf] + c * 4096 + w * 1024);
    }
    {
      int flat = tid * 16;
      int row = flat >> 6, colb = flat & 63;
      int gcolb = colb ^ ((row & 3) << 4);
      gload_lds16(Bb + ((size_t)(h * 64 + row) * 160 + tk * 32) * 2 + gcolb,
                  Bs[buf] + w * 1024);
    }
  };

  stage(0, 0);
  __syncthreads();
  int cur = 0;
  for (int kt = 0; kt < 5; kt++) {
    if (kt < 4) stage(kt + 1, cur ^ 1);
    bf16x8 af[2], bf[4];
    int cs = lk ^ xr;
#pragma unroll
    for (int mf = 0; mf < 2; mf++) af[mf] = *(const bf16x8*)(As[cur] + (w * 32 + mf * 16 + lr) * 64 + cs);
#pragma unroll
    for (int nf = 0; nf < 4; nf++) bf[nf] = *(const bf16x8*)(Bs[cur] + (nf * 16 + lr) * 64 + cs);
#pragma unroll
    for (int mf = 0; mf < 2; mf++)
#pragma unroll
      for (int nf = 0; nf < 4; nf++)
        acc[mf][nf] = __builtin_amdgcn_mfma_f32_16x16x32_bf16(af[mf], bf[nf], acc[mf][nf], 0, 0, 0);
    __syncthreads();
    cur ^= 1;
  }

  int lg = l >> 4;
#pragma unroll
  for (int mf = 0; mf < 2; mf++) {
#pragma unroll
    for (int j = 0; j < 4; j++) {
      int n = nt * 128 + w * 32 + mf * 16 + lg * 4 + j;
      float dnv = den[n * 8 + h];
      float inv = dnv > 0.f ? 1.f / dnv : 0.f;
#pragma unroll
      for (int nf = 0; nf < 4; nf++) {
        int gi = (n << 9) + h * 64 + nf * 16 + lr;
        out[gi] = ((float)numb[gi] + acc[mf][nf][j]) * inv;
      }
    }
  }
}

extern "C" void kernel_launch(void* const* d_in, const int* in_sizes, int n_in,
                              void* d_out, int out_size, void* d_ws, size_t ws_size,
                              hipStream_t stream) {
  const float* xF = (const float*)d_in[0];
  const float* xC = (const float*)d_in[1];
  const int* pairs = (const int*)d_in[2];
  const float* W = (const float*)d_in[3];
  const float* bias = (const float*)d_in[4];
  const float* qt = (const float*)d_in[5];
  const float* kt = (const float*)d_in[6];
  const float* vt = (const float*)d_in[7];
  float* out = (float*)d_out;

  char* ws = (char*)d_ws;
  size_t o = 0;
  auto alloc = [&](size_t bytes) {
    void* p = ws + o;
    o = (o + bytes + 255) & ~(size_t)255;
    return p;
  };
  // region 0: A+BT live only until gemm; Hb (written by attn, later) aliases them.
  char* region0 = (char*)alloc((size_t)N_PTS * 1280 * 2);  // 20.97 MB
  __bf16* A = (__bf16*)region0;                      // 8 MB
  __bf16* BT = (__bf16*)(region0 + (size_t)N_PTS * CIN * 2);  // 1.5 MB
  __bf16* Hb = (__bf16*)region0;                     // aliases A/BT after gemm
  __bf16* qb = (__bf16*)alloc((size_t)N_PTS * 512 * 2);
  __bf16* kv = (__bf16*)alloc((size_t)N_PTS * 1024 * 2);  // k|v interleaved, 2KB rows
  __bf16* qtb = (__bf16*)alloc((size_t)8 * 144 * 64 * 2);
  __bf16* ktb = (__bf16*)alloc((size_t)8 * 144 * 64 * 2);
  __bf16* vtT = (__bf16*)alloc((size_t)8 * 64 * 160 * 2);
  __bf16* qdot = (__bf16*)alloc((size_t)N_PTS * 1152 * 2);
  __bf16* kdot = (__bf16*)alloc((size_t)N_PTS * 1152 * 2);
  __bf16* numb = (__bf16*)alloc((size_t)N_PTS * 512 * 2);
  float* den = (float*)alloc((size_t)N_PTS * 8 * 4);
  int* qi_a = (int*)alloc(M_EDGES * 4);
  unsigned* pack0 = (unsigned*)alloc(M_EDGES * 4);
  unsigned* epack = (unsigned*)alloc(M_EDGES * 4);
  int* cnt = (int*)alloc(N_PTS * 4);
  int* off = (int*)alloc((N_PTS + 1) * 4);
  int* cursor = (int*)alloc(N_PTS * 4);
  int* qperm = (int*)alloc(N_PTS * 4);

  hipMemsetAsync(cnt, 0, N_PTS * 4, stream);

  prep_kernel<<<3936, 256, 0, stream>>>(xF, W, qt, kt, vt, pairs, xC,
                                        A, BT, qtb, ktb, vtT, qi_a, pack0, cnt);
  gemm_scan_kernel<<<769, 256, 0, stream>>>(A, BT, bias, qb, kv, cnt, off, cursor, qperm);
  td_scatter_kernel<<<1536, 256, 0, stream>>>(qb, kv, qtb, ktb, qdot, kdot,
                                              qi_a, pack0, cursor, epack);
  attn_kernel<<<N_PTS, 256, 0, stream>>>(qb, kv, qdot, kdot, off, epack, qperm,
                                         numb, den, Hb);
  finish_kernel<<<dim3(N_PTS / 128, 8), 256, 0, stream>>>(Hb, vtT, numb, den, out);
}